// Round 1
// baseline (293.765 us; speedup 1.0000x reference)
//
#include <hip/hip_runtime.h>
#include <math.h>

#define TILE_W 64
#define TILE_H 4
#define HALO 4
#define TWX (TILE_W + 2*HALO)   // 72
#define TWY (TILE_H + 2*HALO)   // 12
#define NST (TWX*TWY)           // 864

// tbl layout in d_ws (floats):
// [0..23] cos_q, [24..47] sin_q, [48..71] cos_q*scale, [72..95] sin_q*scale,
// [96..103] w_n, [104] 1/route_temp, [105] gamma, [106] gain_clipped
__global__ __launch_bounds__(64) void gp_setup(const float* __restrict__ gain,
                                               const float* __restrict__ lrt,
                                               const float* __restrict__ rlg,
                                               float* __restrict__ tbl) {
  int t = threadIdx.x;
  __shared__ float wtmp[8];
  if (t < 8) {
    float tn = (float)(t + 1) * 0.375f;         // t_n = (n+1)/8*3, exact in fp32
    wtmp[t] = expf(-0.5f * tn * tn);
  }
  if (t < 24) {
    float th = (6.283185307179586f * (float)t) / 24.0f;  // match jax fp32 order
    float c = cosf(th), s = sinf(th);
    const float sc = (float)(512.0 / 511.0);
    tbl[t]      = c;
    tbl[24 + t] = s;
    tbl[48 + t] = c * sc;
    tbl[72 + t] = s * sc;
  }
  __syncthreads();
  if (t == 0) {
    float sum = 0.f;
    for (int n = 0; n < 8; ++n) sum += wtmp[n];
    for (int n = 0; n < 8; ++n) tbl[96 + n] = wtmp[n] / sum;
    float rt = expf(lrt[0]);
    rt = fminf(fmaxf(rt, 0.001f), 2.0f);
    float sg = 1.0f / (1.0f + expf(-rlg[0]));
    float rho = sg * 0.95f + 0.05f;
    tbl[104] = 1.0f / rt;
    tbl[105] = 1.0f / (rho + 1e-8f);
    tbl[106] = fmaxf(gain[0], 0.001f);
  }
}

__global__ __launch_bounds__(256) void gp_main(const float* __restrict__ x,
                                               const float* __restrict__ Wb,
                                               const float* __restrict__ cen,
                                               const float* __restrict__ tbl,
                                               float* __restrict__ out) {
  __shared__ float  Fm[NST];
  __shared__ float  Sm[NST];
  __shared__ float4 Qd[NST];   // 2x2 quad of Fm per cell -> 1 ds_read_b128/sample

  const int tx = threadIdx.x;           // 0..63 (one wave per pixel row)
  const int ty = threadIdx.y;           // 0..3
  const int tid = ty * 64 + tx;
  const int bx0 = blockIdx.x * TILE_W - HALO;
  const int by0 = blockIdx.y * TILE_H - HALO;
  const int b = blockIdx.z;
  const float* __restrict__ x0p = x + (size_t)b * 2 * 512 * 512;
  const float* __restrict__ x1p = x0p + 512 * 512;

  // Stage Fm = |x|, Sm = x0+x1 with zero halo (implements both zeros-padding
  // for the conv AND the zeroed bilinear weights for OOB taps).
  #pragma unroll
  for (int it = 0; it < 4; ++it) {
    int idx = tid + it * 256;
    if (idx < NST) {
      int r = idx / TWX, c = idx - r * TWX;
      int gy = by0 + r, gx = bx0 + c;
      float a = 0.f, bv = 0.f;
      if ((unsigned)gx < 512u && (unsigned)gy < 512u) {
        size_t o = (size_t)gy * 512 + gx;
        a = x0p[o];
        bv = x1p[o];
      }
      Fm[idx] = sqrtf(a * a + bv * bv);
      Sm[idx] = a + bv;
    }
  }
  __syncthreads();
  #pragma unroll
  for (int it = 0; it < 4; ++it) {
    int idx = tid + it * 256;
    if (idx < NST) {
      int r = idx / TWX, c = idx - r * TWX;
      int r1 = (r < TWY - 1) ? r + 1 : r;
      int c1 = (c < TWX - 1) ? c + 1 : c;
      Qd[idx] = make_float4(Fm[r * TWX + c],  Fm[r * TWX + c1],
                            Fm[r1 * TWX + c], Fm[r1 * TWX + c1]);
    }
  }
  __syncthreads();

  const int gi = bx0 + HALO + tx;
  const int gj = by0 + HALO + ty;
  const float SC = (float)(512.0 / 511.0);
  const float ax = (float)gi * SC - 0.5f;
  const float ay = (float)gj * SC - 0.5f;

  float wn[8];
  #pragma unroll
  for (int n = 0; n < 8; ++n) wn[n] = tbl[96 + n];

  // Orientation energy: 24 angles x 8 radii bilinear samples of Fm.
  // atan2 is scale-invariant -> no softmax normalization or max-subtract
  // needed (E in [0,~8], exp safe in fp32).
  float SY = 0.f, CX = 0.f;
  for (int q = 0; q < 24; ++q) {
    const float csx = tbl[48 + q];   // uniform s_load
    const float ssy = tbl[72 + q];
    float e = 0.f;
    #pragma unroll
    for (int n = 0; n < 8; ++n) {
      const float tn = 0.375f * (float)(n + 1);
      float px = fmaf(-csx, tn, ax);
      float py = fmaf(-ssy, tn, ay);
      float fpx = floorf(px), fpy = floorf(py);
      float fx = px - fpx, fy = py - fpy;
      int lx = (int)fpx - bx0;         // in [tx, tx+7] subset of [0,70]
      int ly = (int)fpy - by0;         // in [ty, ty+7] subset of [0,10]
      float4 v = Qd[ly * TWX + lx];
      float wx0 = 1.f - fx, wy0 = 1.f - fy;
      float s = wy0 * (wx0 * v.x + fx * v.y) + fy * (wx0 * v.z + fx * v.w);
      e = fmaf(wn[n], s, e);
    }
    e = expf(e);
    SY = fmaf(e, tbl[24 + q], SY);
    CX = fmaf(e, tbl[q], CX);
  }

  // 7x7 conv of (x0+x1) against 4 orientation banks (uniform s_load weights).
  float a0 = 0.f, a1 = 0.f, a2 = 0.f, a3 = 0.f;
  #pragma unroll
  for (int kj = 0; kj < 7; ++kj) {
    #pragma unroll
    for (int ki = 0; ki < 7; ++ki) {
      float s = Sm[(ty + 1 + kj) * TWX + (tx + 1 + ki)];
      int k = kj * 7 + ki;
      a0 = fmaf(s, Wb[k], a0);
      a1 = fmaf(s, Wb[49 + k], a1);
      a2 = fmaf(s, Wb[98 + k], a2);
      a3 = fmaf(s, Wb[147 + k], a3);
    }
  }

  // theta = atan2 mod pi
  const float TP  = 6.283185307179586f;
  const float PIF = 3.14159265358979323846f;
  const float HP  = 1.57079632679489661923f;
  float hat = atan2f(SY, CX);
  float r1 = fmodf(hat + TP, TP);     // hat+2pi >= pi > 0
  float theta = fmodf(r1, PIF);

  const float irt   = tbl[104];
  const float gamma = tbl[105];
  const float gainc = tbl[106];

  float dist[4];
  #pragma unroll
  for (int o = 0; o < 4; ++o) {
    float d = theta - cen[o] + HP;
    float dd = fmodf(d, PIF);
    dd = (dd < 0.f) ? dd + PIF : dd;
    dist[o] = fabsf(dd - HP);
  }
  float mn = fminf(fminf(dist[0], dist[1]), fminf(dist[2], dist[3]));
  float eo[4], Z = 0.f;
  #pragma unroll
  for (int o = 0; o < 4; ++o) { eo[o] = expf((mn - dist[o]) * irt); Z += eo[o]; }
  float invZ = 1.0f / Z;
  float sh[4], Zs = 0.f;
  #pragma unroll
  for (int o = 0; o < 4; ++o) { sh[o] = powf(fmaf(eo[o], invZ, 1e-12f), gamma); Zs += sh[o]; }
  float wsi = 1.0f / (Zs + 1e-8f);
  float ov = (a0 * sh[0] + a1 * sh[1] + a2 * sh[2] + a3 * sh[3]) * wsi;

  out[((size_t)b * 512 + gj) * 512 + gi] = gainc * ov;
}

extern "C" void kernel_launch(void* const* d_in, const int* in_sizes, int n_in,
                              void* d_out, int out_size, void* d_ws, size_t ws_size,
                              hipStream_t stream) {
  const float* x    = (const float*)d_in[0];
  const float* gain = (const float*)d_in[1];
  const float* lrt  = (const float*)d_in[2];
  const float* rlg  = (const float*)d_in[3];
  const float* Wb   = (const float*)d_in[4];
  const float* cen  = (const float*)d_in[5];
  float* tbl = (float*)d_ws;

  gp_setup<<<1, 64, 0, stream>>>(gain, lrt, rlg, tbl);

  dim3 grid(512 / TILE_W, 512 / TILE_H, 8);
  dim3 blk(TILE_W, TILE_H);
  gp_main<<<grid, blk, 0, stream>>>(x, Wb, cen, tbl, (float*)d_out);
}

// Round 2
// 146.534 us; speedup vs baseline: 2.0048x; 2.0048x over previous
//
#include <hip/hip_runtime.h>
#include <math.h>

#define TILE_W 64
#define TILE_H 4
#define HALO 4
#define TWX (TILE_W + 2*HALO)   // 72
#define TWY (TILE_H + 2*HALO)   // 12
#define NST (TWX*TWY)           // 864

#if __has_builtin(__builtin_amdgcn_fractf)
#define FRACTF(x) __builtin_amdgcn_fractf(x)
#else
#define FRACTF(x) ((x) - floorf(x))
#endif
#if __has_builtin(__builtin_amdgcn_exp2f)
#define EXP2F(x) __builtin_amdgcn_exp2f(x)
#else
#define EXP2F(x) exp2f(x)
#endif
#if __has_builtin(__builtin_amdgcn_logf)
#define LOG2F(x) __builtin_amdgcn_logf(x)
#else
#define LOG2F(x) log2f(x)
#endif

// tbl layout (floats):
// [0..23] cos_q   [24..47] sin_q   [48..71] cos_q*SC   [72..95] sin_q*SC
// [96..103] wn_norm * log2(e)
// [104] (1/route_temp)*log2(e)   [105] gamma   [106] gain_clipped
// [107] dense flag (int)
// [108..139] conv tap weights [4][8]
// [140..171] conv tap deltas  [4][8] (int, element offset kj*TWX+ki)
__global__ __launch_bounds__(64) void gp_setup(const float* __restrict__ gain,
                                               const float* __restrict__ lrt,
                                               const float* __restrict__ rlg,
                                               const float* __restrict__ Wb,
                                               float* __restrict__ tbl) {
  int t = threadIdx.x;
  __shared__ float wtmp[8];
  if (t < 8) {
    float tn = (float)(t + 1) * 0.375f;         // t_n = (n+1)/8*3, exact fp32
    wtmp[t] = expf(-0.5f * tn * tn);
  }
  if (t < 24) {
    float th = (6.283185307179586f * (float)t) / 24.0f;  // match jax fp32 order
    float c = cosf(th), s = sinf(th);
    const float sc = (float)(512.0 / 511.0);
    tbl[t]      = c;
    tbl[24 + t] = s;
    tbl[48 + t] = c * sc;
    tbl[72 + t] = s * sc;
  }
  __syncthreads();
  if (t == 0) {
    const float L2E = 1.44269504088896340736f;
    float sum = 0.f;
    for (int n = 0; n < 8; ++n) sum += wtmp[n];
    for (int n = 0; n < 8; ++n) tbl[96 + n] = (wtmp[n] / sum) * L2E;
    float rt = expf(lrt[0]);
    rt = fminf(fmaxf(rt, 0.001f), 2.0f);
    float sg = 1.0f / (1.0f + expf(-rlg[0]));
    float rho = sg * 0.95f + 0.05f;
    tbl[104] = (1.0f / rt) * L2E;
    tbl[105] = 1.0f / (rho + 1e-8f);
    tbl[106] = fmaxf(gain[0], 0.001f);
    // Sparse conv tap extraction: each 7x7 bank is a line mask (~7 nonzeros).
    int* ti = (int*)tbl;
    int dense = 0;
    for (int o = 0; o < 4; ++o) {
      int cnt = 0;
      for (int k = 0; k < 49; ++k) {
        float w = Wb[o * 49 + k];
        if (w != 0.0f) {
          if (cnt < 8) {
            int kj = k / 7, ki = k - kj * 7;
            tbl[108 + o * 8 + cnt] = w;
            ti[140 + o * 8 + cnt] = kj * TWX + ki;
          }
          cnt++;
        }
      }
      if (cnt > 8) dense = 1;
      for (int c2 = cnt; c2 < 8; ++c2) { tbl[108 + o * 8 + c2] = 0.f; ti[140 + o * 8 + c2] = 0; }
    }
    ti[107] = dense;
  }
}

__global__ __launch_bounds__(256) void gp_main(const float* __restrict__ x,
                                               const float* __restrict__ Wb,
                                               const float* __restrict__ cen,
                                               const float* __restrict__ tbl,
                                               float* __restrict__ out) {
  __shared__ float  Fm[NST];
  __shared__ float  Sm[NST];
  __shared__ float4 Qd[NST];   // pre-differenced 2x2 quad: bilinear = 1 mul + 3 fma

  const int tx = threadIdx.x;           // 0..63 (one wave per pixel row)
  const int ty = threadIdx.y;           // 0..3
  const int tid = ty * 64 + tx;
  const int bx0 = blockIdx.x * TILE_W - HALO;
  const int by0 = blockIdx.y * TILE_H - HALO;
  const int b = blockIdx.z;
  const float* __restrict__ x0p = x + (size_t)b * 2 * 512 * 512;
  const float* __restrict__ x1p = x0p + 512 * 512;

  // Stage Fm = |x|, Sm = x0+x1 with zero halo (zeros-padding for conv AND
  // zeroed bilinear OOB weights fall out automatically).
  #pragma unroll
  for (int it = 0; it < 4; ++it) {
    int idx = tid + it * 256;
    if (idx < NST) {
      int r = idx / TWX, c = idx - r * TWX;
      int gy = by0 + r, gx = bx0 + c;
      float a = 0.f, bv = 0.f;
      if ((unsigned)gx < 512u && (unsigned)gy < 512u) {
        size_t o = (size_t)gy * 512 + gx;
        a = x0p[o];
        bv = x1p[o];
      }
      Fm[idx] = sqrtf(a * a + bv * bv);
      Sm[idx] = a + bv;
    }
  }
  __syncthreads();
  // Pre-differenced quads: s = v.x + fx*v.y + fy*v.z + fx*fy*v.w
  #pragma unroll
  for (int it = 0; it < 4; ++it) {
    int idx = tid + it * 256;
    if (idx < NST) {
      int r = idx / TWX, c = idx - r * TWX;
      int r1 = (r < TWY - 1) ? r + 1 : r;
      int c1 = (c < TWX - 1) ? c + 1 : c;
      float v00 = Fm[r * TWX + c],  v01 = Fm[r * TWX + c1];
      float v10 = Fm[r1 * TWX + c], v11 = Fm[r1 * TWX + c1];
      Qd[idx] = make_float4(v00, v01 - v00, v10 - v00, (v11 - v10) - (v01 - v00));
    }
  }
  __syncthreads();

  const int gi = bx0 + HALO + tx;
  const int gj = by0 + HALO + ty;
  const float SC = (float)(512.0 / 511.0);
  // Local (tile-frame) sample coords are always > 0 -> (int) trunc == floor.
  const float axl = fmaf((float)gi, SC, -0.5f) - (float)bx0;
  const float ayl = fmaf((float)gj, SC, -0.5f) - (float)by0;

  float wn[8];
  #pragma unroll
  for (int n = 0; n < 8; ++n) wn[n] = tbl[96 + n];   // pre-scaled by log2(e)

  // Orientation energy: 24 angles x 8 radii bilinear samples of Fm.
  // atan2 is scale-invariant -> no softmax normalization needed; E*log2e fits
  // v_exp_f32 directly.
  float SY = 0.f, CX = 0.f;
  for (int q = 0; q < 24; ++q) {
    const float csx = tbl[48 + q];   // uniform s_load
    const float ssy = tbl[72 + q];
    float e2 = 0.f;
    #pragma unroll
    for (int n = 0; n < 8; ++n) {
      const float tn = 0.375f * (float)(n + 1);
      float px = fmaf(-csx, tn, axl);
      float py = fmaf(-ssy, tn, ayl);
      int ix = (int)px;              // trunc == floor (px > 0)
      int iy = (int)py;
      float fx = FRACTF(px);
      float fy = FRACTF(py);
      float4 v = Qd[iy * TWX + ix];
      float fxy = fx * fy;
      float s = fmaf(fx, v.y, v.x);
      s = fmaf(fy, v.z, s);
      s = fmaf(fxy, v.w, s);
      e2 = fmaf(wn[n], s, e2);
    }
    float e = EXP2F(e2);
    SY = fmaf(e, tbl[24 + q], SY);
    CX = fmaf(e, tbl[q], CX);
  }

  // Conv: sparse tap lists (7 nonzeros per line-mask bank), dense fallback.
  const int* ti = (const int*)tbl;
  const int cbase = (ty + 1) * TWX + tx + 1;
  float a0 = 0.f, a1 = 0.f, a2 = 0.f, a3 = 0.f;
  if (ti[107] == 0) {
    #pragma unroll
    for (int t2 = 0; t2 < 8; ++t2) {
      a0 = fmaf(Sm[cbase + ti[140 + t2]],      tbl[108 + t2],      a0);
      a1 = fmaf(Sm[cbase + ti[148 + t2]],      tbl[116 + t2],      a1);
      a2 = fmaf(Sm[cbase + ti[156 + t2]],      tbl[124 + t2],      a2);
      a3 = fmaf(Sm[cbase + ti[164 + t2]],      tbl[132 + t2],      a3);
    }
  } else {
    #pragma unroll
    for (int kj = 0; kj < 7; ++kj) {
      #pragma unroll
      for (int ki = 0; ki < 7; ++ki) {
        float s = Sm[(ty + 1 + kj) * TWX + (tx + 1 + ki)];
        int k = kj * 7 + ki;
        a0 = fmaf(s, Wb[k], a0);
        a1 = fmaf(s, Wb[49 + k], a1);
        a2 = fmaf(s, Wb[98 + k], a2);
        a3 = fmaf(s, Wb[147 + k], a3);
      }
    }
  }

  // theta = atan2 mod pi. Conditional subtracts are Sterbenz-exact here and
  // bit-identical to fmodf on these ranges.
  const float TP  = 6.283185307179586f;
  const float PIF = 3.14159265358979323846f;
  const float HP  = 1.57079632679489661923f;
  float hat = atan2f(SY, CX);
  float r1 = hat + TP;                       // (pi, 3pi]
  r1 = (r1 >= TP) ? (r1 - TP) : r1;          // == fmodf(hat+TP, TP)
  float theta = (r1 >= PIF) ? (r1 - PIF) : r1;  // == fmodf(r1, PIF)

  const float irt2  = tbl[104];
  const float gamma = tbl[105];
  const float gainc = tbl[106];

  float dist[4];
  #pragma unroll
  for (int o = 0; o < 4; ++o) {
    float d = theta - cen[o] + HP;           // in (-1.2, 4.33)
    d -= (d >= PIF) ? PIF : 0.f;             // == fmodf(d, PIF) on this range
    d += (d < 0.f) ? PIF : 0.f;
    dist[o] = fabsf(d - HP);
  }
  float mn = fminf(fminf(dist[0], dist[1]), fminf(dist[2], dist[3]));
  float m2 = mn * irt2;
  float eo[4], Z = 0.f;
  #pragma unroll
  for (int o = 0; o < 4; ++o) { eo[o] = EXP2F(fmaf(-irt2, dist[o], m2)); Z += eo[o]; }
  float invZ = 1.0f / Z;
  float sh[4], Zs = 0.f;
  #pragma unroll
  for (int o = 0; o < 4; ++o) {
    sh[o] = EXP2F(gamma * LOG2F(fmaf(eo[o], invZ, 1e-12f)));
    Zs += sh[o];
  }
  float wsi = 1.0f / (Zs + 1e-8f);
  float ov = (a0 * sh[0] + a1 * sh[1] + a2 * sh[2] + a3 * sh[3]) * wsi;

  out[((size_t)b * 512 + gj) * 512 + gi] = gainc * ov;
}

extern "C" void kernel_launch(void* const* d_in, const int* in_sizes, int n_in,
                              void* d_out, int out_size, void* d_ws, size_t ws_size,
                              hipStream_t stream) {
  const float* x    = (const float*)d_in[0];
  const float* gain = (const float*)d_in[1];
  const float* lrt  = (const float*)d_in[2];
  const float* rlg  = (const float*)d_in[3];
  const float* Wb   = (const float*)d_in[4];
  const float* cen  = (const float*)d_in[5];
  float* tbl = (float*)d_ws;

  gp_setup<<<1, 64, 0, stream>>>(gain, lrt, rlg, Wb, tbl);

  dim3 grid(512 / TILE_W, 512 / TILE_H, 8);
  dim3 blk(TILE_W, TILE_H);
  gp_main<<<grid, blk, 0, stream>>>(x, Wb, cen, tbl, (float*)d_out);
}